// Round 10
// baseline (158.580 us; speedup 1.0000x reference)
//
#include <hip/hip_runtime.h>

#define NT 256
#define RCHUNK 16
#define NSLOT 32
#define RWP 80   // f2 pairs per parity buffer (max RW=72, padded)

typedef float f2 __attribute__((ext_vector_type(2)));

__device__ __forceinline__ float ccval(float sI, float sJ, float sII, float sJJ,
                                       float sIJ, float inv_ws) {
    float cross = fmaf(-(sI * sJ), inv_ws, sIJ);
    float iv    = fmaf(-(sI * sI), inv_ws, sII);
    float jv    = fmaf(-(sJ * sJ), inv_ws, sJJ);
    float den   = fmaf(iv, jv, 1e-8f);
    return (cross * cross) * __builtin_amdgcn_rcpf(den);
}

struct St { float J, i0, i1, i2, i3; };

// Wave-autonomous, zero sync instructions. Wave owns 64 cols x RCHUNK rows.
// Per row: ds_write {I,J} pair -> issue next row's loads -> wavefront fence
// (compiler-only ordering; a wave's DS ops complete in program order in HW)
// -> WIN x ds_read_b64 taps -> compute. Vertical 5-stat sliding window in a
// register ring with compile-time slots.
template<int W, int WIN, int S>
__device__ void level_wave(const float* __restrict__ yh,
                           const float* __restrict__ y,
                           int sub, float* __restrict__ ws_acc, int level,
                           f2* __restrict__ slab, int wid)
{
    constexpr int HW = WIN / 2;
    constexpr int RW = 64 + 2 * HW;
    constexpr int T  = RCHUNK + 2 * HW;
    constexpr int G  = (T + WIN - 1) / WIN;
    constexpr int WRAP = RW - 64;
    constexpr int OFF = (S - 2) / 2;
    constexpr float INV_WS = 1.0f / (float)(WIN * WIN);
    constexpr int STRIPS = W / 64;
    constexpr int CHUNKS = W / RCHUNK;

    int b     = sub / (STRIPS * CHUNKS);
    int rem   = sub - b * (STRIPS * CHUNKS);
    int chunk = rem / STRIPS;
    int strip = rem - chunk * STRIPS;
    int r0 = chunk * RCHUNK;
    int c0 = strip * 64;

    const float* Jb = yh + (size_t)b * W * W;
    const float* Yb = y  + (size_t)b * 512 * 512;

    int l  = threadIdx.x & 63;
    int jA = c0 - HW + l;
    int jB = jA + 64;

    auto fetch1 = [&](int rr, int j, St& s) {
        s.J = 0.f; s.i0 = 0.f; s.i1 = 0.f; s.i2 = 0.f; s.i3 = 0.f;
        int r = r0 - HW + rr;
        if (rr < T && r >= 0 && r < W && j >= 0 && j < W) {
            s.J = Jb[(long)r * W + j];
            if constexpr (S == 1) {
                s.i0 = Yb[(long)r * 512 + j];
            } else {
                const float* p = Yb + (long)(S * r + OFF) * 512 + (S * j + OFF);
                s.i0 = p[0]; s.i1 = p[1]; s.i2 = p[512]; s.i3 = p[513];
            }
        }
    };
    auto ival = [&](const St& s) -> float {
        if constexpr (S == 1) return s.i0;
        else return 0.25f * ((s.i0 + s.i1) + (s.i2 + s.i3));
    };

    float rI[WIN], rJ[WIN], rII[WIN], rJJ[WIN], rIJ[WIN];
#pragma unroll
    for (int k = 0; k < WIN; ++k) { rI[k]=0.f; rJ[k]=0.f; rII[k]=0.f; rJJ[k]=0.f; rIJ[k]=0.f; }
    float vI=0.f, vJ=0.f, vII=0.f, vJJ=0.f, vIJ=0.f;
    float l2acc = 0.f, ccacc = 0.f;

    St sA, sB;
    fetch1(0, jA, sA);
    sB.J = 0.f; sB.i0 = 0.f; sB.i1 = 0.f; sB.i2 = 0.f; sB.i3 = 0.f;
    if (l < WRAP) fetch1(0, jB, sB);

    for (int g = 0; g < G; ++g) {
#pragma unroll
        for (int u = 0; u < WIN; ++u) {
            int rr = g * WIN + u;
            f2* buf = slab + (size_t)(rr & 1) * RWP;   // LDS pointer arith

            // 1) stage row rr as interleaved {I,J} pairs (ds_write_b64)
            {
                f2 vA; vA.x = ival(sA); vA.y = sA.J;
                buf[l] = vA;
                if (l < WRAP) { f2 vB; vB.x = ival(sB); vB.y = sB.J; buf[64 + l] = vB; }
            }
            // 2) issue next row's global loads (in flight until next iter's stage)
            fetch1(rr + 1, jA, sA);
            if (l < WRAP) fetch1(rr + 1, jB, sB);
            // 3) compiler-only ordering; no instructions at wavefront scope
            __builtin_amdgcn_fence(__ATOMIC_ACQ_REL, "wavefront");
            // 4) taps + compute
            if (rr < T) {
                float sIs=0.f, sJs=0.f, sIIs=0.f, sJJs=0.f, sIJs=0.f, Ic=0.f, Jc=0.f;
#pragma unroll
                for (int k = 0; k < WIN; ++k) {
                    f2 v = buf[l + k];          // same base reg + offset:8k
                    float I = v.x, J = v.y;
                    if (k == HW) { Ic = I; Jc = J; }
                    sIs += I; sJs += J;
                    sIIs = fmaf(I, I, sIIs);
                    sJJs = fmaf(J, J, sJJs);
                    sIJs = fmaf(I, J, sIJs);
                }
                if (rr >= HW && rr < HW + RCHUNK) {
                    float d = Jc - Ic;
                    l2acc = fmaf(d, d, l2acc);
                }
                rI[u]=sIs; rJ[u]=sJs; rII[u]=sIIs; rJJ[u]=sJJs; rIJ[u]=sIJs;
                vI+=sIs; vJ+=sJs; vII+=sIIs; vJJ+=sJJs; vIJ+=sIJs;
                if (rr >= 2 * HW) {
                    ccacc += ccval(vI, vJ, vII, vJJ, vIJ, INV_WS);
                    const int uo = (u + 1) % WIN;   // compile-time after unroll
                    vI-=rI[uo]; vJ-=rJ[uo]; vII-=rII[uo]; vJJ-=rJJ[uo]; vIJ-=rIJ[uo];
                }
            }
        }
    }

#pragma unroll
    for (int off = 32; off > 0; off >>= 1) {
        l2acc += __shfl_down(l2acc, off);
        ccacc += __shfl_down(ccacc, off);
    }
    if (l == 0) {
        int slot = wid & (NSLOT - 1);
        atomicAdd(&ws_acc[(level * 2 + 0) * NSLOT + slot], l2acc);
        atomicAdd(&ws_acc[(level * 2 + 1) * NSLOT + slot], ccacc);
    }
}

__global__ __launch_bounds__(NT)
void hier_loss_kernel(const float* __restrict__ yh0, const float* __restrict__ yh1,
                      const float* __restrict__ yh2, const float* __restrict__ yh3,
                      const float* __restrict__ y, float* ws_acc)
{
    __shared__ f2 slab[4][2][RWP];   // 4 waves x 2 parity x 80 pairs = 5120 B
    int wave = threadIdx.x >> 6;
    f2* ws = &slab[wave][0][0];

    int wid = blockIdx.x * (NT / 64) + wave;
    // L0: 8 strips x 32 chunks x 32 = 8192      -> [0, 8192)
    // L1: 4 x 16 x 32 = 2048                    -> [8192, 10240)
    // L2: 2 x 8 x 32  = 512                     -> [10240, 10752)
    // L3: 1 x 4 x 32  = 128                     -> [10752, 10880)
    if (wid < 8192) {
        level_wave<512, 9, 1>(yh0, y, wid, ws_acc, 0, ws, wid);
    } else if (wid < 10240) {
        level_wave<256, 9, 2>(yh1, y, wid - 8192, ws_acc, 1, ws, wid);
    } else if (wid < 10752) {
        level_wave<128, 7, 4>(yh2, y, wid - 10240, ws_acc, 2, ws, wid);
    } else {
        level_wave<64, 5, 8>(yh3, y, wid - 10752, ws_acc, 3, ws, wid);
    }
}

__global__ void hier_finalize_kernel(const float* __restrict__ ws_acc, float* __restrict__ out)
{
    if (threadIdx.x == 0 && blockIdx.x == 0) {
        const float wts[4] = {1.0f, 0.5f, 0.25f, 0.125f};
        float total = 0.f;
#pragma unroll
        for (int lv = 0; lv < 4; ++lv) {
            float l2s = 0.f, ccs = 0.f;
            for (int s = 0; s < NSLOT; ++s) {
                l2s += ws_acc[(lv * 2 + 0) * NSLOT + s];
                ccs += ws_acc[(lv * 2 + 1) * NSLOT + s];
            }
            float l2  = l2s / 32.0f;
            float ncc = -ccs / (32.0f * 100.0f);
            float ll  = wts[lv] * (l2 + ncc) * 0.5f;
            out[1 + lv] = ll;
            total += ll;
        }
        out[0] = total;
    }
}

extern "C" void kernel_launch(void* const* d_in, const int* in_sizes, int n_in,
                              void* d_out, int out_size, void* d_ws, size_t ws_size,
                              hipStream_t stream)
{
    const float* yh0 = (const float*)d_in[0];
    const float* yh1 = (const float*)d_in[1];
    const float* yh2 = (const float*)d_in[2];
    const float* yh3 = (const float*)d_in[3];
    const float* y   = (const float*)d_in[4];
    float* ws_acc = (float*)d_ws;
    float* out = (float*)d_out;

    hipMemsetAsync(ws_acc, 0, 8 * NSLOT * sizeof(float), stream);
    hier_loss_kernel<<<10880 / (NT / 64), NT, 0, stream>>>(yh0, yh1, yh2, yh3, y, ws_acc);
    hier_finalize_kernel<<<1, 64, 0, stream>>>(ws_acc, out);
}